// Round 5
// baseline (216.479 us; speedup 1.0000x reference)
//
#include <hip/hip_runtime.h>

// SpatioConvLayer: B=16, C_IN=C_OUT=64, T=12, N=1024, KS=3
#define NB   16
#define NC   64
#define NT   12
#define NN   1024
#define NKS  3

typedef float  f32x4  __attribute__((ext_vector_type(4)));
typedef float  f32x16 __attribute__((ext_vector_type(16)));
typedef short  s16x8  __attribute__((ext_vector_type(8)));
typedef unsigned short u16x4 __attribute__((ext_vector_type(4)));
typedef unsigned short u16x8 __attribute__((ext_vector_type(8)));
typedef unsigned short ush;

__device__ __forceinline__ ush f2bf(float f) {
    union { float f; unsigned u; } v; v.f = f;
    unsigned r = v.u + 0x7FFFu + ((v.u >> 16) & 1u);   // RNE
    return (ush)(r >> 16);
}

// Workspace layout (frag-ordered panels for 32x32x16 MFMA; 16-B chunk per lane):
//   apan @ 0        : bf16 A-frags [g2=96][s=64][fidA=4][lane=64] x 16B  (25,165,824 B)
//                     fidA = wr*2 + fa ; lane l: element
//                     A[row = 64*wr + 32*fa + (l&31)][k = s*16 + (l>>5)*8 + i]
//   kb   @ 25165824 : bf16 B-frags [mt=16][s=64][fidB=6][lane=64] x 16B  (6,291,456 B)
//                     fidB = wn*3 + fb ; lane l: element
//                     B[j = 96*wn + 32*fb + (l&31)][k = s*16 + (l>>5)*8 + i]
//                     where B[j][n] = kern[n][col(j)], col(j) = (j>>6)*1024 + mt*64 + (j&63)
//   thbf @ 31457280 : bf16 theta^T [o=64][ck=192]                        (24,576 B)
#define APAN_OFF 0
#define KB_OFF   25165824
#define TH_OFF   31457280

// ---------------- prep: convert + transpose into fragment order ----------------
// Block map: [0,6144) A-frags, [6144,6528) B-frags (coalesced transpose),
//            [6528,6576) theta.
__global__ __launch_bounds__(256)
void spatio_prep(const float* __restrict__ x, const float* __restrict__ kern,
                 const float* __restrict__ theta,
                 ush* __restrict__ apan, ush* __restrict__ kb, ush* __restrict__ thbf)
{
    const int blk = blockIdx.x;
    const int tid = threadIdx.x;

    if (blk < 6144) {
        // ---- A frags: one 16-B chunk per thread; lanes l and l+32 consume one
        //      full 64-B line of x (no overfetch); writes perfectly linear. ----
        int id   = blk * 256 + tid;           // ((g2*64 + s)*4 + fid)*64 + lane
        int lane = id & 63;
        int fid  = (id >> 6) & 3;
        int s    = (id >> 8) & 63;
        int g2   = id >> 14;
        int h    = lane >> 5, l32 = lane & 31;
        int wr = fid >> 1, fa = fid & 1;
        int c  = 32 * fa + l32;               // row within bt = c channel
        int bt = 2 * g2 + wr;
        int b  = bt / NT, t = bt - NT * b;
        int koff = s * 16 + h * 8;
        const float* src = x + ((size_t)((b * NC + c) * NT + t)) * NN + koff;
        float4 a0 = ((const float4*)src)[0];
        float4 a1 = ((const float4*)src)[1];
        u16x8 w;
        w[0] = f2bf(a0.x); w[1] = f2bf(a0.y); w[2] = f2bf(a0.z); w[3] = f2bf(a0.w);
        w[4] = f2bf(a1.x); w[5] = f2bf(a1.y); w[6] = f2bf(a1.z); w[7] = f2bf(a1.w);
        ((u16x8*)apan)[id] = w;
    } else if (blk < 6528) {
        // ---- B frags: coalesced transpose. thread = (mt,s,fid,h,l8):
        //      reads 8 kern rows x float4 (4 cols), writes 4 lanes' chunks (64 B). ----
        int id   = (blk - 6144) * 256 + tid;  // 0..98303
        int l8   = id & 7;
        int h    = (id >> 3) & 1;
        int fid  = (id >> 4) % 6;
        int rest = (id >> 4) / 6;             // 0..1023
        int s    = rest & 63;
        int mt   = rest >> 6;
        int wn   = fid / 3, fb = fid - 3 * wn;
        int j0   = 96 * wn + 32 * fb + 4 * l8;
        int kbig = j0 >> 6, mm0 = j0 & 63;
        int col0 = (kbig << 10) + (mt << 6) + mm0;
        int n0   = s * 16 + h * 8;
        float4 v[8];
#pragma unroll
        for (int i = 0; i < 8; ++i)
            v[i] = *(const float4*)&kern[(size_t)(n0 + i) * (NKS * NN) + col0];
        int cb = ((mt * 64 + s) * 6 + fid) * 64 + h * 32 + 4 * l8;
#pragma unroll
        for (int jj = 0; jj < 4; ++jj) {
            u16x8 w;
            w[0] = f2bf(v[0][jj]); w[1] = f2bf(v[1][jj]);
            w[2] = f2bf(v[2][jj]); w[3] = f2bf(v[3][jj]);
            w[4] = f2bf(v[4][jj]); w[5] = f2bf(v[5][jj]);
            w[6] = f2bf(v[6][jj]); w[7] = f2bf(v[7][jj]);
            ((u16x8*)kb)[cb + jj] = w;
        }
    } else {
        // ---- theta^T: thbf[o][k*64+c] ----
        int id = (blk - 6528) * 256 + tid;
        if (id < 12288) {
            int row = id >> 6, o = id & 63;   // row = c*3 + k
            int c = row / 3, k = row - 3 * c;
            thbf[o * 192 + k * 64 + c] = f2bf(theta[id]);
        }
    }
}

// ---------------- main: 128x192 tile, register-resident K-loop, 32x32x16 MFMA ----------------
// 4 waves (2 bt-halves x 2 col-halves), per-wave 64x96 = 2x3 fragments of 32x32.
// Stage 1: global->reg fragment loads, 2-set pipeline (1 half-step ahead),
//          ZERO barriers. LDS only for stage-2 xm (25.6 KB).
__global__ __launch_bounds__(256, 2)
void spatio_main(const ush* __restrict__ apan, const ush* __restrict__ kb,
                 const ush* __restrict__ thbf, const float* __restrict__ bias,
                 const float* __restrict__ x, float* __restrict__ out)
{
    __shared__ __attribute__((aligned(128))) char smem[25600];
    ush (*xm)[200] = (ush (*)[200])smem;     // [mm][ck] stage-2 operand

    const int tid  = threadIdx.x;
    const int g2   = blockIdx.x;          // bt-pair 0..95 (g2%8 -> fixed XCD: A panel XCD-local)
    const int mt   = blockIdx.y;          // m-tile 0..15
    const int m_base = mt * 64;
    const int lane = tid & 63;
    const int wid  = tid >> 6;            // 0..3
    const int wr   = wid & 1;             // bt half (64 rows)
    const int wn   = wid >> 1;            // col half (96 j)
    const int quad = lane >> 4;
    const int l16  = lane & 15;
    const int h5   = lane >> 5;
    const int l32  = lane & 31;

    const ush* Abp = apan + (size_t)g2 * 131072 + (wr * 2) * 512 + lane * 8;
    const ush* Bbp = kb   + (size_t)mt * 196608 + (wn * 3) * 512 + lane * 8;

    f32x16 acc[2][3];
#pragma unroll
    for (int i = 0; i < 2; ++i)
#pragma unroll
        for (int j = 0; j < 3; ++j)
#pragma unroll
            for (int e = 0; e < 16; ++e) acc[i][j][e] = 0.f;

    // ===== stage 1: 2-set register pipeline over 32 half-steps (K=32 each) =====
    // half-step hh covers s = 2*hh, 2*hh+1 ; per set: 4 A-frags + 6 B-frags.
    s16x8 Pa[4], Pb[6], Qa[4], Qb[6];

#define LOADSET(S, hh) do {                                                       \
        _Pragma("unroll")                                                         \
        for (int ss = 0; ss < 2; ++ss) {                                          \
            _Pragma("unroll")                                                     \
            for (int fa = 0; fa < 2; ++fa)                                        \
                S##a[2 * ss + fa] =                                               \
                    *(const s16x8*)(Abp + (2 * (hh) + ss) * 2048 + fa * 512);     \
            _Pragma("unroll")                                                     \
            for (int fb = 0; fb < 3; ++fb)                                        \
                S##b[3 * ss + fb] =                                               \
                    *(const s16x8*)(Bbp + (2 * (hh) + ss) * 3072 + fb * 512);     \
        }                                                                         \
    } while (0)

#define COMPUTE(S) do {                                                           \
        _Pragma("unroll")                                                         \
        for (int ss = 0; ss < 2; ++ss)                                            \
            _Pragma("unroll")                                                     \
            for (int fa = 0; fa < 2; ++fa)                                        \
                _Pragma("unroll")                                                 \
                for (int fb = 0; fb < 3; ++fb)                                    \
                    acc[fa][fb] = __builtin_amdgcn_mfma_f32_32x32x16_bf16(        \
                        S##a[2 * ss + fa], S##b[3 * ss + fb], acc[fa][fb], 0, 0, 0);\
    } while (0)

    LOADSET(P, 0);
    for (int hh = 0; hh < 32; hh += 2) {
        LOADSET(Q, hh + 1);
        COMPUTE(P);                        // half-step hh
        if (hh + 2 < 32) LOADSET(P, hh + 2);
        COMPUTE(Q);                        // half-step hh+1
    }

#undef LOADSET
#undef COMPUTE

    // ===== stage 2: gc = th^T @ xm ; one bt per pass =====
    float bo[4];
#pragma unroll
    for (int r = 0; r < 4; ++r) bo[r] = bias[16 * wid + 4 * quad + r];

    for (int pass = 0; pass < 2; ++pass) {
        __syncthreads();               // previous-pass xm readers done
        if (wr == pass) {
            // write acc -> xm[mm][k*64+c] (stage-2 B-operand layout)
            // 32x32 C/D: col = l32, row = (reg&3) + 8*(reg>>2) + 4*h5
#pragma unroll
            for (int fa = 0; fa < 2; ++fa)
#pragma unroll
                for (int fb = 0; fb < 3; ++fb) {
                    int J   = 96 * wn + 32 * fb + l32;
                    int kkb = J >> 6, mm = J & 63;
#pragma unroll
                    for (int rg = 0; rg < 4; ++rg) {
                        int c0 = 32 * fa + 8 * rg + 4 * h5;
                        u16x4 w;
                        w.x = f2bf(acc[fa][fb][4 * rg + 0]);
                        w.y = f2bf(acc[fa][fb][4 * rg + 1]);
                        w.z = f2bf(acc[fa][fb][4 * rg + 2]);
                        w.w = f2bf(acc[fa][fb][4 * rg + 3]);
                        *(u16x4*)&xm[mm][kkb * 64 + c0] = w;
                    }
                }
        }
        __syncthreads();

        f32x4 acc2[4];
#pragma unroll
        for (int jb = 0; jb < 4; ++jb) acc2[jb] = (f32x4){0.f, 0.f, 0.f, 0.f};
#pragma unroll
        for (int ks = 0; ks < 6; ++ks) {       // K = 192
            s16x8 a2 = *(const s16x8*)(thbf + (size_t)(16 * wid + l16) * 192 + ks * 32 + quad * 8);
#pragma unroll
            for (int jb = 0; jb < 4; ++jb) {
                s16x8 b2 = *(const s16x8*)&xm[16 * jb + l16][ks * 32 + quad * 8];
                acc2[jb] = __builtin_amdgcn_mfma_f32_16x16x32_bf16(a2, b2, acc2[jb], 0, 0, 0);
            }
        }

        // epilogue: out = relu(gc + bias + x) ; residual read f32 from x directly
        const int bt = 2 * g2 + pass;
        const int b2i = bt / NT, t2 = bt - NT * b2i;
#pragma unroll
        for (int jb = 0; jb < 4; ++jb) {
            int mm = 16 * jb + l16;
#pragma unroll
            for (int r = 0; r < 4; ++r) {
                int o = 16 * wid + 4 * quad + r;
                size_t idx = (((size_t)(b2i * NC + o) * NT + t2) * NN) + m_base + mm;
                float v = acc2[jb][r] + bo[r] + x[idx];
                out[idx] = fmaxf(v, 0.f);
            }
        }
    }
}

extern "C" void kernel_launch(void* const* d_in, const int* in_sizes, int n_in,
                              void* d_out, int out_size, void* d_ws, size_t ws_size,
                              hipStream_t stream) {
    const float* x     = (const float*)d_in[0];
    const float* kern  = (const float*)d_in[1];
    const float* theta = (const float*)d_in[2];
    const float* bias  = (const float*)d_in[3];
    float* out = (float*)d_out;
    (void)in_sizes; (void)n_in; (void)out_size; (void)ws_size;

    ush* apan = (ush*)((char*)d_ws + APAN_OFF);
    ush* kbp  = (ush*)((char*)d_ws + KB_OFF);
    ush* thbf = (ush*)((char*)d_ws + TH_OFF);

    hipLaunchKernelGGL(spatio_prep, dim3(6576), dim3(256), 0, stream,
                       x, kern, theta, apan, kbp, thbf);
    hipLaunchKernelGGL(spatio_main, dim3(96, 16), dim3(256), 0, stream,
                       apan, kbp, thbf, bias, x, out);
}

// Round 7
// 210.486 us; speedup vs baseline: 1.0285x; 1.0285x over previous
//
#include <hip/hip_runtime.h>

// SpatioConvLayer: B=16, C_IN=C_OUT=64, T=12, N=1024, KS=3
#define NB   16
#define NC   64
#define NT   12
#define NN   1024
#define NKS  3

typedef float  f32x4  __attribute__((ext_vector_type(4)));
typedef short  s16x8  __attribute__((ext_vector_type(8)));
typedef unsigned short u16x4 __attribute__((ext_vector_type(4)));
typedef unsigned short u16x8 __attribute__((ext_vector_type(8)));
typedef unsigned short ush;

__device__ __forceinline__ ush f2bf(float f) {
    union { float f; unsigned u; } v; v.f = f;
    unsigned r = v.u + 0x7FFFu + ((v.u >> 16) & 1u);   // RNE
    return (ush)(r >> 16);
}

// async 16-B global -> LDS (dest = wave-uniform base + lane*16; 16B is the
// HW-verified width — size 12 caused R6's correctness failure, do not use)
__device__ __forceinline__ void cp16(const void* g, void* l) {
    __builtin_amdgcn_global_load_lds(
        (const __attribute__((address_space(1))) unsigned int*)g,
        (__attribute__((address_space(3))) unsigned int*)l, 16, 0, 0);
}

// Workspace layout (K=32 subtile panels, byte-linear images of the LDS slots):
//   apan @ 0        : [g4=48][sub=32] A-subtile = 1024 x 16B chunks  (25,165,824 B)
//                     chunk c: r=c>>2, p=c&3, d=p^(r&3); r=bl*64+ch (bl=bt-4*g4)
//                     holds x[bt, ch, k = sub*32 + d*8 .. +8] as bf16
//   kb   @ 25165824 : [mt=16][sub=32] B-subtile = 768 x 16B chunks   (6,291,456 B)
//                     chunk s: j=s>>2, p=s&3, d=p^(j&3); holds
//                     B[j][k=sub*32+d*8..+8], B[j][n]=kern[n][(j>>6)*1024+mt*64+(j&63)]
//   thbf @ 31457280 : bf16 theta^T [o=64][ck=192]                    (24,576 B)
#define APAN_OFF 0
#define KB_OFF   25165824
#define TH_OFF   31457280

// ---------------- prep: convert + transpose into subtile order ----------------
// Block map: [0,6144) A, [6144,6528) B (coalesced transpose), [6528,6576) theta.
__global__ __launch_bounds__(256)
void spatio_prep(const float* __restrict__ x, const float* __restrict__ kern,
                 const float* __restrict__ theta,
                 ush* __restrict__ apan, ush* __restrict__ kb, ush* __restrict__ thbf)
{
    const int blk = blockIdx.x;
    const int tid = threadIdx.x;

    if (blk < 6144) {
        // ---- A: one 16-B chunk/thread; 4 p-lanes of a row consume 128 B of x ----
        int id  = blk * 256 + tid;            // ((g4*32+sub)*1024) + c
        int c   = id & 1023;
        int sub = (id >> 10) & 31;
        int g4  = id >> 15;
        int r   = c >> 2, p = c & 3;
        int d   = p ^ (r & 3);
        int bl  = r >> 6, ch = r & 63;
        int bt  = 4 * g4 + bl;
        int b   = bt / NT, t = bt - NT * b;
        const float* src = x + ((size_t)((b * NC + ch) * NT + t)) * NN + sub * 32 + d * 8;
        float4 a0 = ((const float4*)src)[0];
        float4 a1 = ((const float4*)src)[1];
        u16x8 w;
        w[0] = f2bf(a0.x); w[1] = f2bf(a0.y); w[2] = f2bf(a0.z); w[3] = f2bf(a0.w);
        w[4] = f2bf(a1.x); w[5] = f2bf(a1.y); w[6] = f2bf(a1.z); w[7] = f2bf(a1.w);
        ((u16x8*)apan)[id] = w;
    } else if (blk < 6528) {
        // ---- B: coalesced transpose. thread = (mt,sub,jq,d): reads 8 rows x float4
        //      (16 jq-lanes cover 256 B of each kern row), writes 4 chunks (64 B). ----
        int id  = (blk - 6144) * 256 + tid;   // 0..98303
        int d   = id & 3;
        int jq  = (id >> 2) % 48;
        int r2  = (id >> 2) / 48;
        int sub = r2 & 31;
        int mt  = r2 >> 5;
        int j0  = jq * 4;
        int colbase = ((j0 >> 6) << 10) + (mt << 6) + (j0 & 63);
        int n0  = sub * 32 + d * 8;
        float4 v[8];
#pragma unroll
        for (int i = 0; i < 8; ++i)
            v[i] = *(const float4*)&kern[(size_t)(n0 + i) * (NKS * NN) + colbase];
        int cbase = (mt * 32 + sub) * 768;
#pragma unroll
        for (int jj = 0; jj < 4; ++jj) {
            u16x8 w;
            w[0] = f2bf(v[0][jj]); w[1] = f2bf(v[1][jj]);
            w[2] = f2bf(v[2][jj]); w[3] = f2bf(v[3][jj]);
            w[4] = f2bf(v[4][jj]); w[5] = f2bf(v[5][jj]);
            w[6] = f2bf(v[6][jj]); w[7] = f2bf(v[7][jj]);
            ((u16x8*)kb)[cbase + (j0 + jj) * 4 + (d ^ jj)] = w;
        }
    } else {
        // ---- theta^T: thbf[o][k*64+c] ----
        int id = (blk - 6528) * 256 + tid;
        if (id < 12288) {
            int row = id >> 6, o = id & 63;   // row = c*3 + k
            int c = row / 3, k = row - 3 * c;
            thbf[o * 192 + k * 64 + c] = f2bf(theta[id]);
        }
    }
}

// ---------------- main: 256x192 tile, 4-slot ring, counted vmcnt (T3+T4) ----------------
// 512 thr / 8 waves (4 bt-rows x 2 col-halves); per-wave 64x96 = 4x6 16x16 frags.
// Ring slot = K=32 subtile: A[256][32] 16 KB + B[192][32] 12 KB = 28 KB; 4 slots.
// Staging: slot = 1792 x 16B chunks; threads 0..447 do 4 cp16 each (A/B boundary
// at chunk 1024 falls on a wave boundary -> every instr has wave-uniform LDS base).
// Wave 7 issues no loads; its counted vmcnt waits are trivially satisfied.
// Per iter: vmcnt(8) retires subtile t only (t+1,t+2 stay in flight; never drain
// to 0 mid-loop); 1 barrier; STAGE(t+3) issued 3 iters (~1400 cy) ahead of use.
__global__ __launch_bounds__(512, 2)
void spatio_main(const ush* __restrict__ apan, const ush* __restrict__ kb,
                 const ush* __restrict__ thbf, const float* __restrict__ bias,
                 const float* __restrict__ x, float* __restrict__ out)
{
    __shared__ __attribute__((aligned(128))) char smem[114688];

    const int tid  = threadIdx.x;
    const int g4   = blockIdx.x;          // bt-quad 0..47 (g4%8 -> XCD pin, A panel L2-local)
    const int mt   = blockIdx.y;          // m-tile 0..15
    const int lane = tid & 63;
    const int wid  = tid >> 6;            // 0..7
    const int wr   = wid >> 1;            // bt-row 0..3
    const int wn   = wid & 1;             // col half 0..1
    const int quad = lane >> 4;
    const int l16  = lane & 15;
    const int swz16 = (quad ^ (l16 & 3)) << 4;   // byte offset of 16-B chunk in 64-B row

    const char* abase = (const char*)apan + (size_t)g4 * 524288;   // g4*32*16384
    const char* bbase = (const char*)kb   + (size_t)mt * 393216;   // mt*32*12288

    // per-wave LDS read offsets within a slot
    int aoff[4], boff[6];
#pragma unroll
    for (int rb = 0; rb < 4; ++rb)
        aoff[rb] = (64 * wr + 16 * rb + l16) * 64 + swz16;
#pragma unroll
    for (int jb = 0; jb < 6; ++jb)
        boff[jb] = 16384 + (96 * wn + 16 * jb + l16) * 64 + swz16;

    f32x4 acc[4][6];
#pragma unroll
    for (int i = 0; i < 4; ++i)
#pragma unroll
        for (int j = 0; j < 6; ++j) acc[i][j] = (f32x4){0.f, 0.f, 0.f, 0.f};

    // stage subtile tt into ring slot tt&3 (4 x cp16 per thread, threads 0..447)
#define STAGE(tt) do {                                                        \
        const char* as_ = abase + (size_t)(tt) * 16384;                       \
        const char* bs_ = bbase + (size_t)(tt) * 12288;                       \
        char* sl_ = smem + ((tt) & 3) * 28672;                                \
        if (tid < 448) {                                                      \
            _Pragma("unroll")                                                 \
            for (int i_ = 0; i_ < 4; ++i_) {                                  \
                int c_ = i_ * 448 + tid;                                      \
                const char* g_ = (c_ < 1024) ? (as_ + c_ * 16)                \
                                             : (bs_ + (c_ - 1024) * 16);      \
                cp16(g_, sl_ + c_ * 16);                                      \
            }                                                                 \
        }                                                                     \
    } while (0)

    STAGE(0); STAGE(1); STAGE(2);

    for (int t = 0; t < 32; ++t) {
        // retire exactly subtile t's 4 loads; keep t+1,t+2 (8 loads) in flight
        if (t < 30)       asm volatile("s_waitcnt vmcnt(8)" ::: "memory");
        else if (t == 30) asm volatile("s_waitcnt vmcnt(4)" ::: "memory");
        else              asm volatile("s_waitcnt vmcnt(0)" ::: "memory");
        __builtin_amdgcn_s_barrier();      // slot t ready; slot (t+3)&3 readers done
        asm volatile("" ::: "memory");
        if (t + 3 < 32) STAGE(t + 3);
        const char* sl = smem + (t & 3) * 28672;
        s16x8 af[4], bf[6];
#pragma unroll
        for (int rb = 0; rb < 4; ++rb) af[rb] = *(const s16x8*)(sl + aoff[rb]);
#pragma unroll
        for (int jb = 0; jb < 6; ++jb) bf[jb] = *(const s16x8*)(sl + boff[jb]);
        asm volatile("s_waitcnt lgkmcnt(0)" ::: "memory");
        __builtin_amdgcn_sched_barrier(0);
        __builtin_amdgcn_s_setprio(1);
#pragma unroll
        for (int rb = 0; rb < 4; ++rb)
#pragma unroll
            for (int jb = 0; jb < 6; ++jb)
                acc[rb][jb] = __builtin_amdgcn_mfma_f32_16x16x32_bf16(
                    af[rb], bf[jb], acc[rb][jb], 0, 0, 0);
        __builtin_amdgcn_s_setprio(0);
    }
#undef STAGE

    // ===== stage 2: xm for all 4 bt at once, overlaying the ring =====
    ush (*xm)[64][200] = (ush (*)[64][200])smem;   // [bt][mm][ck], 102,400 B
    __syncthreads();                     // all slot readers done before overwrite
#pragma unroll
    for (int rb = 0; rb < 4; ++rb)
#pragma unroll
        for (int jb = 0; jb < 6; ++jb) {
            int J   = 96 * wn + 16 * jb + l16;
            int kk2 = J >> 6, mm = J & 63;
            int ck0 = (kk2 << 6) + 16 * rb + (quad << 2);
            u16x4 w;
            w.x = f2bf(acc[rb][jb].x); w.y = f2bf(acc[rb][jb].y);
            w.z = f2bf(acc[rb][jb].z); w.w = f2bf(acc[rb][jb].w);
            *(u16x4*)&xm[wr][mm][ck0] = w;
        }
    __syncthreads();

    // gc = th^T @ xm : wave wid -> bt = wid&3, mm-half = wid>>2
    const int bt2 = wid & 3, hh = wid >> 2;
    f32x4 acc2[4][2];
#pragma unroll
    for (int i = 0; i < 4; ++i) {
        acc2[i][0] = (f32x4){0.f, 0.f, 0.f, 0.f};
        acc2[i][1] = (f32x4){0.f, 0.f, 0.f, 0.f};
    }
#pragma unroll
    for (int ks = 0; ks < 6; ++ks) {       // K = 192
        s16x8 b2[2];
#pragma unroll
        for (int jm = 0; jm < 2; ++jm)
            b2[jm] = *(const s16x8*)&xm[bt2][(hh << 5) + (jm << 4) + l16]
                                            [(ks << 5) + (quad << 3)];
#pragma unroll
        for (int of = 0; of < 4; ++of) {
            s16x8 a2 = *(const s16x8*)(thbf + (size_t)((of << 4) + l16) * 192
                                            + (ks << 5) + (quad << 3));
#pragma unroll
            for (int jm = 0; jm < 2; ++jm)
                acc2[of][jm] = __builtin_amdgcn_mfma_f32_16x16x32_bf16(
                    a2, b2[jm], acc2[of][jm], 0, 0, 0);
        }
    }

    // epilogue: out = relu(gc + bias + x), residual read f32 from x directly
    const int bt = (g4 << 2) + bt2;
    const int b  = bt / NT, tt = bt - NT * b;
#pragma unroll
    for (int of = 0; of < 4; ++of)
#pragma unroll
        for (int jm = 0; jm < 2; ++jm) {
            int mm = (hh << 5) + (jm << 4) + l16;
#pragma unroll
            for (int r = 0; r < 4; ++r) {
                int o = (of << 4) + (quad << 2) + r;
                size_t idx = ((size_t)((b * NC + o) * NT + tt)) * NN + (mt << 6) + mm;
                float v = acc2[of][jm][r] + bias[o] + x[idx];
                out[idx] = fmaxf(v, 0.f);
            }
        }
}

extern "C" void kernel_launch(void* const* d_in, const int* in_sizes, int n_in,
                              void* d_out, int out_size, void* d_ws, size_t ws_size,
                              hipStream_t stream) {
    const float* x     = (const float*)d_in[0];
    const float* kern  = (const float*)d_in[1];
    const float* theta = (const float*)d_in[2];
    const float* bias  = (const float*)d_in[3];
    float* out = (float*)d_out;
    (void)in_sizes; (void)n_in; (void)out_size; (void)ws_size;

    ush* apan = (ush*)((char*)d_ws + APAN_OFF);
    ush* kbp  = (ush*)((char*)d_ws + KB_OFF);
    ush* thbf = (ush*)((char*)d_ws + TH_OFF);

    hipLaunchKernelGGL(spatio_prep, dim3(6576), dim3(256), 0, stream,
                       x, kern, theta, apan, kbp, thbf);
    hipLaunchKernelGGL(spatio_main, dim3(48, 16), dim3(512), 0, stream,
                       apan, kbp, thbf, bias, x, out);
}